// Round 9
// baseline (388.850 us; speedup 1.0000x reference)
//
#include <hip/hip_runtime.h>
#include <cstdint>
#include <cstddef>

#define Tt 2048
#define Hh 1024
#define Ff 3584
#define Ee 8
#define ROWS_CAP 6400
#define NP 7168   // 2*Ff, h13 output width

#define OFF_CTRL   0u
#define OFF_TOKE   4096u
#define OFF_TOKW   (4096u + 16384u)
#define OFF_ROWMAP 65536u
#define OFF_ROWW   98304u
#define OFF_XG     (1ull << 20)
#define OFF_H      (16ull << 20)

typedef __attribute__((ext_vector_type(8))) short bf16x8;
typedef __attribute__((ext_vector_type(4))) float f32x4;

__device__ __forceinline__ unsigned short f2bf(float f) {
  unsigned int u = __float_as_uint(f);
  u += 0x7fffu + ((u >> 16) & 1u);
  return (unsigned short)(u >> 16);
}

__device__ __forceinline__ unsigned pkbf(float a, float b) {
  unsigned r;
  asm("v_cvt_pk_bf16_f32 %0, %1, %2" : "=v"(r) : "v"(a), "v"(b));
  return r;
}

__device__ __forceinline__ void gload_lds16(const void* g, void* l) {
  auto gp = (const __attribute__((address_space(1))) char*)(uintptr_t)g;
  auto lp = (__attribute__((address_space(3))) char*)(uintptr_t)l;
  __builtin_amdgcn_global_load_lds(gp, lp, 16, 0, 0);
}

// LDS tile: R rows x 32 k bf16 (64 B/row); chunk gc at pos = gc ^ ((row>>1)&3).
__device__ __forceinline__ bf16x8 frg(const char* lds, int row, int gc) {
  return *(const bf16x8*)(lds + row * 64 + ((gc ^ ((row >> 1) & 3)) * 16));
}

// ---------------- router ----------------
__global__ __launch_bounds__(256) void router_kernel(
    const float* __restrict__ x, const float* __restrict__ gw,
    float* __restrict__ logits_out, int* __restrict__ tok_e,
    float* __restrict__ tok_w, int* __restrict__ ctrl) {
  const int lane = threadIdx.x & 63;
  const int t = blockIdx.x * 4 + (threadIdx.x >> 6);
  const float4* xp = (const float4*)(x + (size_t)t * Hh + lane * 16);
  float4 x0 = xp[0], x1 = xp[1], x2 = xp[2], x3 = xp[3];
  float lg[Ee];
#pragma unroll
  for (int e = 0; e < Ee; ++e) {
    const float4* gp = (const float4*)(gw + e * Hh + lane * 16);
    float4 g0 = gp[0], g1 = gp[1], g2 = gp[2], g3 = gp[3];
    float s = x0.x*g0.x + x0.y*g0.y + x0.z*g0.z + x0.w*g0.w
            + x1.x*g1.x + x1.y*g1.y + x1.z*g1.z + x1.w*g1.w
            + x2.x*g2.x + x2.y*g2.y + x2.z*g2.z + x2.w*g2.w
            + x3.x*g3.x + x3.y*g3.y + x3.z*g3.z + x3.w*g3.w;
#pragma unroll
    for (int o = 32; o; o >>= 1) s += __shfl_xor(s, o);
    lg[e] = s;
  }
  if (lane == 0) {
    float m = lg[0];
#pragma unroll
    for (int e = 1; e < Ee; ++e) m = fmaxf(m, lg[e]);
    float p[Ee];
#pragma unroll
    for (int e = 0; e < Ee; ++e) p[e] = expf(lg[e] - m);
    int a0 = 0;
#pragma unroll
    for (int e = 1; e < Ee; ++e) if (p[e] > p[a0]) a0 = e;
    int a1 = (a0 == 0) ? 1 : 0;
#pragma unroll
    for (int e = 0; e < Ee; ++e) if (e != a0 && p[e] > p[a1]) a1 = e;
    float rs = p[a0] + p[a1];
    float w0 = p[a0] / rs, w1 = p[a1] / rs;
#pragma unroll
    for (int e = 0; e < Ee; ++e) logits_out[(size_t)t * Ee + e] = lg[e];
    tok_e[t * 2] = a0; tok_e[t * 2 + 1] = a1;
    tok_w[t * 2] = w0; tok_w[t * 2 + 1] = w1;
    atomicAdd(&ctrl[a0], 1); atomicAdd(&ctrl[a1], 1);
  }
}

__global__ void offsets_kernel(int* ctrl) {
  if (threadIdx.x == 0) {
    int acc = 0;
    for (int e = 0; e < Ee; ++e) {
      ctrl[16 + e] = acc;
      acc += ((ctrl[e] + 255) >> 8) << 8;   // pad to 256
    }
    ctrl[16 + Ee] = acc;
  }
}

__global__ __launch_bounds__(512) void assign_kernel(
    int* ctrl, const int* __restrict__ tok_e, const float* __restrict__ tok_w,
    int* __restrict__ rowmap, float* __restrict__ roww) {
  int i = blockIdx.x * 512 + threadIdx.x;
  if (i < 2 * Tt) {
    int e = tok_e[i];
    int pos = atomicAdd(&ctrl[8 + e], 1);
    int r = ctrl[16 + e] + pos;
    rowmap[r] = i >> 1;
    roww[r] = tok_w[i];
  }
  if (i < Ee * 256) {
    int e = i >> 8, pd = i & 255;
    int o = ctrl[16 + e], o1 = ctrl[16 + e + 1], c = ctrl[e];
    int r = o + c + pd;
    if (r < o1) { rowmap[r] = -1; roww[r] = 0.f; }
  }
}

// ---------------- gather x rows -> bf16 Xg ----------------
__global__ __launch_bounds__(128) void gather_kernel(
    const float* __restrict__ x, const int* __restrict__ ctrl,
    const int* __restrict__ rowmap, unsigned short* __restrict__ Xg) {
  int r = blockIdx.x;
  if (r >= ctrl[16 + Ee]) return;
  int t = rowmap[r];
  int j = threadIdx.x;
  uint4 v = make_uint4(0u, 0u, 0u, 0u);
  if (t >= 0) {
    const float4* xp = (const float4*)(x + (size_t)t * Hh + j * 8);
    float4 a = xp[0], b = xp[1];
    v.x = (unsigned)f2bf(a.x) | ((unsigned)f2bf(a.y) << 16);
    v.y = (unsigned)f2bf(a.z) | ((unsigned)f2bf(a.w) << 16);
    v.z = (unsigned)f2bf(b.x) | ((unsigned)f2bf(b.y) << 16);
    v.w = (unsigned)f2bf(b.z) | ((unsigned)f2bf(b.w) << 16);
  }
  *(uint4*)(Xg + (size_t)r * Hh + j * 8) = v;
}

// shared MFMA phase macro: wave tile 64x64 over sA[CUR], sB[CUR]
#define MFMA_PHASE(CUR)                                                        \
  { const int gc = lane >> 4;                                                  \
    bf16x8 af[4];                                                              \
    _Pragma("unroll") for (int mi = 0; mi < 4; ++mi)                           \
      af[mi] = frg(sA[CUR], wr * 64 + mi * 16 + (lane & 15), gc);              \
    __builtin_amdgcn_s_setprio(1);                                             \
    _Pragma("unroll") for (int ni = 0; ni < 4; ++ni) {                         \
      bf16x8 bb = frg(sB[CUR], wc * 64 + ni * 16 + (lane & 15), gc);           \
      _Pragma("unroll") for (int mi = 0; mi < 4; ++mi)                         \
        acc[mi][ni] = __builtin_amdgcn_mfma_f32_16x16x32_bf16(af[mi], bb,      \
                                                        acc[mi][ni], 0, 0, 0); \
    }                                                                          \
    __builtin_amdgcn_s_setprio(0); }

// ---------- h13: H[rows, 7168] = Xg @ [w1|w3]^T, BM=BN=256, BK=32, 1024 thr ----------
// d=2 pipeline (R6-proven shape). Ledger at loop barrier: [A(it+1), B(it+2)x8]
// -> vmcnt(8) drains A(it+1); at it==30 no B loads issued -> vmcnt(0).
// Prologue is order-independent: sched_barrier pins, then hard vmcnt(0) drain.
__global__ __launch_bounds__(1024, 4) void h13_gemm(
    const unsigned short* __restrict__ Xg, const float* __restrict__ w1,
    const float* __restrict__ w3, const int* __restrict__ ctrl,
    unsigned short* __restrict__ H) {
  __shared__ alignas(16) char sA[2][16384], sB[2][16384];
  const int lin = blockIdx.x + 28 * blockIdx.y;       // 0..223, z-invariant XCD pin
  const int p = (lin & 7) * 28 + (lin >> 3);
  const int e = p / 28, bx = p % 28, mt = blockIdx.z;
  const int off0 = ctrl[16 + e], off1 = ctrl[16 + e + 1];
  const int row0 = off0 + mt * 256;
  if (row0 >= off1) return;
  const int n0 = bx * 256;                            // n' in [0,7168)
  const float* wsel = (n0 < Ff) ? (w1 + (size_t)e * Hh * Ff + n0)
                                : (w3 + (size_t)e * Hh * Ff + (n0 - Ff));
  const int tid = threadIdx.x, lane = tid & 63, wv = tid >> 6;
  const int wr = wv >> 2, wc = wv & 3;                // 4x4 waves, tile 64x64
  f32x4 acc[4][4] = {};
  const int sgc = (lane & 3) ^ ((lane >> 3) & 3);
  const unsigned short* gA = Xg + (size_t)(row0 + wv * 16 + (lane >> 2)) * Hh + sgc * 8;
  const int bn = tid & 255, bkq = tid >> 8;           // bkq 0..3
  const int wofB = bn * 64 + ((bkq ^ ((bn >> 1) & 3)) * 16);
  const float* pB = wsel + (size_t)(bkq * 8) * Ff + bn;
  float rB[8];

  // ---- prologue: A(0)->sA[0]; B(0)->regs->sB[0]; B(1)->regs; HARD drain ----
  gload_lds16(gA, sA[0] + wv * 1024);
  __builtin_amdgcn_sched_barrier(0);
#pragma unroll
  for (int i = 0; i < 8; ++i) rB[i] = pB[(size_t)i * Ff];
  {
    uint4 q;
    q.x = pkbf(rB[0], rB[1]); q.y = pkbf(rB[2], rB[3]);
    q.z = pkbf(rB[4], rB[5]); q.w = pkbf(rB[6], rB[7]);
    *(uint4*)(sB[0] + wofB) = q;
  }
#pragma unroll
  for (int i = 0; i < 8; ++i) rB[i] = pB[(size_t)(32 + i) * Ff];
  asm volatile("s_waitcnt vmcnt(0) lgkmcnt(0)" ::: "memory");
  __builtin_amdgcn_s_barrier();
  __builtin_amdgcn_sched_barrier(0);

#pragma unroll 2
  for (int it = 0; it < 32; ++it) {
    const int cur = it & 1;
    if (it < 31) gload_lds16(gA + (size_t)(it + 1) * 32, sA[cur ^ 1] + wv * 1024);
    __builtin_amdgcn_sched_barrier(0);
    if (it < 31) {
      uint4 q;
      q.x = pkbf(rB[0], rB[1]); q.y = pkbf(rB[2], rB[3]);
      q.z = pkbf(rB[4], rB[5]); q.w = pkbf(rB[6], rB[7]);
      *(uint4*)(sB[cur ^ 1] + wofB) = q;              // B(it+1), reg-dep drains its loads
    }
    if (it < 30) {
      const float* pw = pB + (size_t)(it + 2) * 32 * Ff;
#pragma unroll
      for (int i = 0; i < 8; ++i) rB[i] = pw[(size_t)i * Ff];
    }
    __builtin_amdgcn_sched_barrier(0);
    MFMA_PHASE(cur)
    if (it < 31) {
      if (it < 30) asm volatile("s_waitcnt vmcnt(8) lgkmcnt(0)" ::: "memory");
      else         asm volatile("s_waitcnt vmcnt(0) lgkmcnt(0)" ::: "memory");
      __builtin_amdgcn_s_barrier();
      __builtin_amdgcn_sched_barrier(0);
    }
  }

  const int rb = wr * 64 + 4 * (lane >> 4), cb = n0 + wc * 64 + (lane & 15);
#pragma unroll
  for (int mi = 0; mi < 4; ++mi)
#pragma unroll
    for (int ni = 0; ni < 4; ++ni)
#pragma unroll
      for (int r = 0; r < 4; ++r)
        H[(size_t)(row0 + rb + mi * 16 + r) * NP + cb + ni * 16] = f2bf(acc[mi][ni][r]);
}

// ---------- ffn2: out[t] += w * (silu(h1)*h3 @ w2^T), BM=BN=256, ksplit x4 ----------
// No async LDS ops: all hazards are reg-dep + lgkmcnt(0) barriers (order-safe).
__device__ __forceinline__ uint4 silu_mul_pack(uint4 a1, uint4 a3) {
  const unsigned* p1 = (const unsigned*)&a1;
  const unsigned* p3 = (const unsigned*)&a3;
  uint4 r;
  unsigned* pr = (unsigned*)&r;
#pragma unroll
  for (int w = 0; w < 4; ++w) {
    float x0 = __uint_as_float((p1[w] & 0xFFFFu) << 16);
    float x1 = __uint_as_float(p1[w] & 0xFFFF0000u);
    float y0 = __uint_as_float((p3[w] & 0xFFFFu) << 16);
    float y1 = __uint_as_float(p3[w] & 0xFFFF0000u);
    float g0 = x0 / (1.f + __expf(-x0)) * y0;
    float g1 = x1 / (1.f + __expf(-x1)) * y1;
    pr[w] = pkbf(g0, g1);
  }
  return r;
}

__global__ __launch_bounds__(1024, 4) void ffn2_gemm(
    const unsigned short* __restrict__ H, const float* __restrict__ w2,
    const int* __restrict__ ctrl, const int* __restrict__ rowmap,
    const float* __restrict__ roww, float* __restrict__ out) {
  __shared__ alignas(16) char sA[2][16384], sB[2][16384];
  const int lin = blockIdx.x + 4 * blockIdx.y;        // 0..31, z-invariant XCD pin
  const int p = (lin & 7) * 4 + (lin >> 3);
  const int e = p >> 2, bx = p & 3;
  const int mt = blockIdx.z >> 2, ks = blockIdx.z & 3;
  const int off0 = ctrl[16 + e], off1 = ctrl[16 + e + 1];
  const int row0 = off0 + mt * 256;
  if (row0 >= off1) return;
  const int n0 = bx * 256;
  const int kb = ks * (Ff / 4);                       // 896-wide K chunk, 28 iters
  const int tid = threadIdx.x, lane = tid & 63, wv = tid >> 6;
  const int wr = wv >> 2, wc = wv & 3;
  f32x4 acc[4][4] = {};
  const int arow = tid >> 2, akq = tid & 3;
  const int wofA = arow * 64 + ((akq ^ ((arow >> 1) & 3)) * 16);
  const unsigned short* pH1 = H + (size_t)(row0 + arow) * NP + kb + akq * 8;
  const unsigned short* pH3 = pH1 + Ff;
  const int bn = tid & 255, bkq = tid >> 8;
  const int wofB = bn * 64 + ((bkq ^ ((bn >> 1) & 3)) * 16);
  const float* pB = w2 + (size_t)e * Ff * Hh + (size_t)(kb + bkq * 8) * Hh + n0 + bn;
  uint4 h1e, h3e, h1o, h3o;
  float bEven[8], bOdd[8];

  // ---- prologue ----
  uint4 tA1 = *(const uint4*)(pH1);
  uint4 tA3 = *(const uint4*)(pH3);
  float tB[8];
#pragma unroll
  for (int i = 0; i < 8; ++i) tB[i] = pB[(size_t)i * Hh];
  h1e = *(const uint4*)(pH1 + 32);  h3e = *(const uint4*)(pH3 + 32);
  h1o = *(const uint4*)(pH1 + 64);  h3o = *(const uint4*)(pH3 + 64);
#pragma unroll
  for (int i = 0; i < 8; ++i) bEven[i] = pB[(size_t)(32 + i) * Hh];
#pragma unroll
  for (int i = 0; i < 8; ++i) bOdd[i] = pB[(size_t)(64 + i) * Hh];
  *(uint4*)(sA[0] + wofA) = silu_mul_pack(tA1, tA3);
  {
    uint4 q;
    q.x = pkbf(tB[0], tB[1]); q.y = pkbf(tB[2], tB[3]);
    q.z = pkbf(tB[4], tB[5]); q.w = pkbf(tB[6], tB[7]);
    *(uint4*)(sB[0] + wofB) = q;
  }
  asm volatile("s_waitcnt lgkmcnt(0)" ::: "memory");
  __builtin_amdgcn_s_barrier();
  __builtin_amdgcn_sched_barrier(0);

#define F2_ITER(IT, CUR, A1, A3, BS)                                           \
  {                                                                            \
    if ((IT) + 1 < 28) {                                                       \
      *(uint4*)(sA[(CUR) ^ 1] + wofA) = silu_mul_pack(A1, A3);                 \
      uint4 q;                                                                 \
      q.x = pkbf(BS[0], BS[1]); q.y = pkbf(BS[2], BS[3]);                      \
      q.z = pkbf(BS[4], BS[5]); q.w = pkbf(BS[6], BS[7]);                      \
      *(uint4*)(sB[(CUR) ^ 1] + wofB) = q;                                     \
    }                                                                          \
    { int w = (IT) + 3; if (w >= 28) w -= 28;                                  \
      A1 = *(const uint4*)(pH1 + (size_t)w * 32);                              \
      A3 = *(const uint4*)(pH3 + (size_t)w * 32);                              \
      const float* pw = pB + (size_t)w * 32 * Hh;                              \
      _Pragma("unroll") for (int i = 0; i < 8; ++i) BS[i] = pw[(size_t)i * Hh]; } \
    __builtin_amdgcn_sched_barrier(0);                                         \
    MFMA_PHASE(CUR)                                                            \
    if ((IT) + 1 < 28) {                                                       \
      asm volatile("s_waitcnt lgkmcnt(0)" ::: "memory");                       \
      __builtin_amdgcn_s_barrier();                                            \
      __builtin_amdgcn_sched_barrier(0);                                       \
    }                                                                          \
  }

  for (int j = 0; j < 14; ++j) {
    const int it0 = 2 * j;
    F2_ITER(it0, 0, h1e, h3e, bEven)
    F2_ITER(it0 + 1, 1, h1o, h3o, bOdd)
  }
#undef F2_ITER

  const int rb = wr * 64 + 4 * (lane >> 4), cb = wc * 64 + (lane & 15);
#pragma unroll
  for (int mi = 0; mi < 4; ++mi)
#pragma unroll
    for (int r = 0; r < 4; ++r) {
      int grow = row0 + rb + mi * 16 + r;
      int t = rowmap[grow];
      if (t < 0) continue;
      float wgt = roww[grow];
#pragma unroll
      for (int ni = 0; ni < 4; ++ni)
        atomicAdd(&out[(size_t)t * Hh + n0 + cb + ni * 16], wgt * acc[mi][ni][r]);
    }
}

extern "C" void kernel_launch(void* const* d_in, const int* in_sizes, int n_in,
                              void* d_out, int out_size, void* d_ws, size_t ws_size,
                              hipStream_t stream) {
  const float* x  = (const float*)d_in[0];
  const float* gw = (const float*)d_in[1];
  const float* w1 = (const float*)d_in[2];
  const float* w3 = (const float*)d_in[3];
  const float* w2 = (const float*)d_in[4];
  float* out = (float*)d_out;
  float* logits = out + (size_t)Tt * Hh;
  char* ws = (char*)d_ws;
  int* ctrl = (int*)(ws + OFF_CTRL);
  int* tok_e = (int*)(ws + OFF_TOKE);
  float* tok_w = (float*)(ws + OFF_TOKW);
  int* rowmap = (int*)(ws + OFF_ROWMAP);
  float* roww = (float*)(ws + OFF_ROWW);
  unsigned short* Xg = (unsigned short*)(ws + OFF_XG);
  unsigned short* H  = (unsigned short*)(ws + OFF_H);

  hipMemsetAsync(ctrl, 0, 256, stream);
  hipMemsetAsync(out, 0, (size_t)Tt * Hh * sizeof(float), stream);
  router_kernel<<<Tt / 4, 256, 0, stream>>>(x, gw, logits, tok_e, tok_w, ctrl);
  offsets_kernel<<<1, 64, 0, stream>>>(ctrl);
  assign_kernel<<<8, 512, 0, stream>>>(ctrl, tok_e, tok_w, rowmap, roww);
  gather_kernel<<<ROWS_CAP, 128, 0, stream>>>(x, ctrl, rowmap, Xg);
  h13_gemm<<<dim3(28, 8, 16), 1024, 0, stream>>>(Xg, w1, w3, ctrl, H);
  ffn2_gemm<<<dim3(4, 8, 64), 1024, 0, stream>>>(H, w2, ctrl, rowmap, roww, out);
}